// Round 3
// baseline (3269.393 us; speedup 1.0000x reference)
//
#include <hip/hip_runtime.h>

// ---------------------------------------------------------------------------
// GraphSAGE 3-layer + MLP head, fp32. N=100000, E=3200000.
// Round 3: bucketed push aggregation. No CSR col fill (R2's 291us hotspot:
// random 4B writes over 12.8MB -> 194MB of partial-line evictions).
//   - partition: LDS-staged histogram scatter into K=ceil(n/128) buckets,
//     runs reserved per (block,bucket) -> write locality ~2.5x ideal.
//   - push64: block per bucket, 128x64 fp32 accumulator in 32KB LDS,
//     ds_add_f32 (lane-striped, 2-way = free), coalesced flush.
// ---------------------------------------------------------------------------

#define RB 128
#define RB_SHIFT 7
#define MAXK 1024  // supports n <= 131072

__global__ void hist_kernel(const int* __restrict__ dst, int* __restrict__ deg, int E) {
    int e = blockIdx.x * blockDim.x + threadIdx.x;
    if (e < E) atomicAdd(&deg[dst[e]], 1);
}

__global__ void scan_blocks_kernel(const int* __restrict__ deg, int* __restrict__ rowptr,
                                   int* __restrict__ blocksum, int n) {
    __shared__ int s[256];
    int base = blockIdx.x * 1024;
    int t = threadIdx.x;
    int v[4];
    int loc = 0;
#pragma unroll
    for (int k = 0; k < 4; k++) {
        int i = base + t * 4 + k;
        v[k] = (i < n) ? deg[i] : 0;
        loc += v[k];
    }
    s[t] = loc;
    __syncthreads();
    for (int off = 1; off < 256; off <<= 1) {
        int xv = (t >= off) ? s[t - off] : 0;
        __syncthreads();
        s[t] += xv;
        __syncthreads();
    }
    if (t == 255) blocksum[blockIdx.x] = s[255];
    int run = s[t] - loc;
#pragma unroll
    for (int k = 0; k < 4; k++) {
        int i = base + t * 4 + k;
        if (i < n) rowptr[i] = run;
        run += v[k];
    }
}

__global__ void scan_sums_kernel(int* __restrict__ blocksum, int nb) {
    __shared__ int s[128];
    int t = threadIdx.x;
    int v = (t < nb) ? blocksum[t] : 0;
    s[t] = v;
    __syncthreads();
    for (int off = 1; off < 128; off <<= 1) {
        int xv = (t >= off) ? s[t - off] : 0;
        __syncthreads();
        s[t] += xv;
        __syncthreads();
    }
    if (t < nb) blocksum[t] = s[t] - v;
}

__global__ void scan_add_kernel(int* __restrict__ rowptr, const int* __restrict__ blocksum, int n) {
    int i = blockIdx.x * blockDim.x + threadIdx.x;
    if (i < n) rowptr[i] += blocksum[i >> 10];
}

__global__ void cursor_init_kernel(const int* __restrict__ rowptr, int* __restrict__ gcur, int K) {
    int b = blockIdx.x * blockDim.x + threadIdx.x;
    if (b < K) gcur[b] = rowptr[b << RB_SHIFT];
}

// Partition edges into K buckets of RB nodes, packed as src | (dst&127)<<20.
// 512 threads, 8192 edges per block. Phase A: LDS bucket hist. Phase B:
// reserve contiguous runs in staging via one global atomic per bucket.
// Phase C: re-read edges (L2-warm), scatter into reserved runs.
__global__ void partition_kernel(const int* __restrict__ src, const int* __restrict__ dst,
                                 int* __restrict__ gcur, unsigned* __restrict__ staging,
                                 int E, int K) {
    __shared__ int cnt[MAXK];
    __shared__ int base[MAXK];
    const int blockBase = blockIdx.x * 8192;
    for (int i = threadIdx.x; i < K; i += 512) cnt[i] = 0;
    __syncthreads();
#pragma unroll
    for (int k = 0; k < 16; k++) {
        int j = blockBase + threadIdx.x + k * 512;
        if (j < E) atomicAdd(&cnt[dst[j] >> RB_SHIFT], 1);
    }
    __syncthreads();
    for (int b = threadIdx.x; b < K; b += 512) {
        int c = cnt[b];
        base[b] = c ? atomicAdd(&gcur[b], c) : 0;
        cnt[b] = 0;
    }
    __syncthreads();
#pragma unroll
    for (int k = 0; k < 16; k++) {
        int j = blockBase + threadIdx.x + k * 512;
        if (j < E) {
            int d = dst[j];
            int b = d >> RB_SHIFT;
            int r = atomicAdd(&cnt[b], 1);
            staging[base[b] + r] = (unsigned)src[j] | ((unsigned)(d & (RB - 1)) << 20);
        }
    }
}

// layer-1 aggregation: block per bucket, 128x4 LDS accumulator
__global__ void push4_kernel(const unsigned* __restrict__ staging, const int* __restrict__ rowptr,
                             const float4* __restrict__ x, float4* __restrict__ agg4,
                             int n, int E, int K) {
    __shared__ float s[RB * 4];
    const int b = blockIdx.x;
    const int base_node = b << RB_SHIFT;
    const int beg = rowptr[base_node];
    const int end = (b == K - 1) ? E : rowptr[base_node + RB];
    for (int i = threadIdx.x; i < RB * 4; i += 256) s[i] = 0.f;
    __syncthreads();
    for (int i = beg + threadIdx.x; i < end; i += 256) {
        unsigned v = staging[i];
        int srcn = v & 0xFFFFF;
        int local = v >> 20;
        float4 xv = x[srcn];
        atomicAdd(&s[local * 4 + 0], xv.x);
        atomicAdd(&s[local * 4 + 1], xv.y);
        atomicAdd(&s[local * 4 + 2], xv.z);
        atomicAdd(&s[local * 4 + 3], xv.w);
    }
    __syncthreads();
    for (int i = threadIdx.x; i < RB; i += 256) {
        int node = base_node + i;
        if (node < n) agg4[node] = make_float4(s[i * 4], s[i * 4 + 1], s[i * 4 + 2], s[i * 4 + 3]);
    }
}

// F=64 aggregation: block (512 thr, 8 waves) per bucket. lane = feature.
// Per edge: broadcast packed int, coalesced 256B gather of h row, ds_add_f32
// into LDS (addr = local*64+lane -> lane-striped banks, 2-way, free).
__global__ void push64_kernel(const unsigned* __restrict__ staging, const int* __restrict__ rowptr,
                              const float* __restrict__ h, float* __restrict__ agg,
                              int n, int E, int K) {
    __shared__ float s[RB * 64];  // 32 KB
    const int b = blockIdx.x;
    const int base_node = b << RB_SHIFT;
    const int beg = rowptr[base_node];
    const int end = (b == K - 1) ? E : rowptr[base_node + RB];
    float4* s4 = (float4*)s;
    for (int i = threadIdx.x; i < RB * 16; i += 512) s4[i] = make_float4(0.f, 0.f, 0.f, 0.f);
    __syncthreads();
    const int wave = threadIdx.x >> 6;
    const int lane = threadIdx.x & 63;
    for (int i = beg + wave; i < end; i += 8) {
        unsigned v = staging[i];
        int srcn = v & 0xFFFFF;
        int local = v >> 20;
        atomicAdd(&s[local * 64 + lane], h[(size_t)srcn * 64 + lane]);
    }
    __syncthreads();
    float4* aggv = (float4*)(agg + (size_t)base_node * 64);
    const int maxv = min(n - base_node, RB) * 16;
    for (int i = threadIdx.x; i < maxv; i += 512) aggv[i] = s4[i];
}

// out[n][j] = relu( (agg[n]/max(deg,1)) @ Wl + b + x[n] @ Wr )
// Rows staged in LDS before any write => `out` may alias `agg`.
template <int FIN, int FOUT>
__global__ void sage_layer_kernel(const float* __restrict__ agg, const int* __restrict__ deg,
                                  const float* __restrict__ x,
                                  const float* __restrict__ Wl, const float* __restrict__ b,
                                  const float* __restrict__ Wr,
                                  float* __restrict__ out, int n) {
    constexpr int NPB = 256 / FOUT;
    __shared__ float sWl[FIN * FOUT];
    __shared__ float sWr[FIN * FOUT];
    __shared__ float sb[FOUT];
    __shared__ float sA[NPB][FIN];
    __shared__ float sX[NPB][FIN];
    for (int i = threadIdx.x; i < FIN * FOUT; i += 256) {
        sWl[i] = Wl[i];
        sWr[i] = Wr[i];
    }
    if (threadIdx.x < FOUT) sb[threadIdx.x] = b[threadIdx.x];
    const int first = blockIdx.x * NPB;
    for (int i = threadIdx.x; i < NPB * FIN; i += 256) {
        int local = i / FIN, k = i % FIN;
        int node = first + local;
        float av = 0.f, xv = 0.f;
        if (node < n) {
            av = agg[(size_t)node * FIN + k];
            xv = x[(size_t)node * FIN + k];
        }
        sA[local][k] = av;
        sX[local][k] = xv;
    }
    __syncthreads();

    const int local = threadIdx.x / FOUT;
    const int j = threadIdx.x % FOUT;
    const int node = first + local;
    if (node >= n) return;
    const float inv = 1.0f / (float)max(deg[node], 1);
    float accA = 0.f, accX = 0.f;
#pragma unroll
    for (int k = 0; k < FIN; k++) {
        accA += sA[local][k] * sWl[k * FOUT + j];
        accX += sX[local][k] * sWr[k * FOUT + j];
    }
    out[(size_t)node * FOUT + j] = fmaxf(sb[j] + inv * accA + accX, 0.0f);
}

__global__ void head_kernel(const float* __restrict__ h3, const float* __restrict__ W4,
                            const float* __restrict__ b4, const float* __restrict__ W5,
                            const float* __restrict__ b5, float* __restrict__ out, int n) {
    __shared__ float sW4[32 * 16];
    __shared__ float sb4[16];
    __shared__ float sW5[16];
    for (int i = threadIdx.x; i < 32 * 16; i += blockDim.x) sW4[i] = W4[i];
    if (threadIdx.x < 16) {
        sb4[threadIdx.x] = b4[threadIdx.x];
        sW5[threadIdx.x] = W5[threadIdx.x];
    }
    __syncthreads();

    int node = blockIdx.x * blockDim.x + threadIdx.x;
    if (node >= n) return;

    float hl[32];
#pragma unroll
    for (int k = 0; k < 32; k++) hl[k] = h3[(size_t)node * 32 + k];

    float acc = b5[0];
#pragma unroll
    for (int j = 0; j < 16; j++) {
        float t = sb4[j];
#pragma unroll
        for (int k = 0; k < 32; k++) t += hl[k] * sW4[k * 16 + j];
        acc += fmaxf(t, 0.0f) * sW5[j];
    }
    out[node] = acc;
}

extern "C" void kernel_launch(void* const* d_in, const int* in_sizes, int n_in,
                              void* d_out, int out_size, void* d_ws, size_t ws_size,
                              hipStream_t stream) {
    const float* x   = (const float*)d_in[0];
    const int*   ei  = (const int*)d_in[1];
    const float* W1l = (const float*)d_in[2];
    const float* b1  = (const float*)d_in[3];
    const float* W1r = (const float*)d_in[4];
    const float* W2l = (const float*)d_in[5];
    const float* b2  = (const float*)d_in[6];
    const float* W2r = (const float*)d_in[7];
    const float* W3l = (const float*)d_in[8];
    const float* b3  = (const float*)d_in[9];
    const float* W3r = (const float*)d_in[10];
    const float* W4  = (const float*)d_in[11];
    const float* b4  = (const float*)d_in[12];
    const float* W5  = (const float*)d_in[13];
    const float* b5  = (const float*)d_in[14];
    float* out = (float*)d_out;

    const int n = in_sizes[0] / 4;
    const int E = in_sizes[1] / 2;
    const int* src = ei;
    const int* dst = ei + E;
    const int K = (n + RB - 1) >> RB_SHIFT;  // 782 for n=100000

    char* ws = (char*)d_ws;
    size_t off = 0;
    auto alloc = [&](size_t bytes) {
        char* p = ws + off;
        off += (bytes + 255) & ~(size_t)255;
        return p;
    };
    int*      deg     = (int*)alloc((size_t)n * sizeof(int));
    int*      rowptr  = (int*)alloc((size_t)n * sizeof(int));
    int*      gcur    = (int*)alloc((size_t)K * sizeof(int));
    int*      bsum    = (int*)alloc(128 * sizeof(int));
    unsigned* staging = (unsigned*)alloc((size_t)E * sizeof(unsigned));  // 12.8MB; reused for h3
    float*    agg4    = (float*)alloc((size_t)n * 4 * sizeof(float));
    float*    agg     = (float*)alloc((size_t)n * 64 * sizeof(float));
    float*    hA      = (float*)alloc((size_t)n * 64 * sizeof(float));
    (void)ws_size;

    const int BT = 256;
    const int nb = (n + 1023) / 1024;  // <=128

    // ---- degree + rowptr + bucketed edge partition ----
    hipMemsetAsync(deg, 0, (size_t)n * sizeof(int), stream);
    hist_kernel<<<(E + BT - 1) / BT, BT, 0, stream>>>(dst, deg, E);
    scan_blocks_kernel<<<nb, 256, 0, stream>>>(deg, rowptr, bsum, n);
    scan_sums_kernel<<<1, 128, 0, stream>>>(bsum, nb);
    scan_add_kernel<<<(n + BT - 1) / BT, BT, 0, stream>>>(rowptr, bsum, n);
    cursor_init_kernel<<<(K + BT - 1) / BT, BT, 0, stream>>>(rowptr, gcur, K);
    partition_kernel<<<(E + 8191) / 8192, 512, 0, stream>>>(src, dst, gcur, staging, E, K);

    // ---- layer 1: x[N,4] -> hA[N,64] ----
    push4_kernel<<<K, 256, 0, stream>>>(staging, rowptr, (const float4*)x, (float4*)agg4, n, E, K);
    sage_layer_kernel<4, 64><<<(n + 3) / 4, 256, 0, stream>>>(agg4, deg, x, W1l, b1, W1r, hA, n);

    // ---- layer 2: hA -> h2 (in-place into agg) ----
    push64_kernel<<<K, 512, 0, stream>>>(staging, rowptr, hA, agg, n, E, K);
    sage_layer_kernel<64, 64><<<(n + 3) / 4, 256, 0, stream>>>(agg, deg, hA, W2l, b2, W2r, agg, n);

    // ---- layer 3: h2=agg -> h3 (staging buffer is dead after this push) ----
    push64_kernel<<<K, 512, 0, stream>>>(staging, rowptr, agg, hA, n, E, K);
    float* h3 = (float*)staging;  // N*32 floats == E uints == 12.8MB
    sage_layer_kernel<64, 32><<<(n + 7) / 8, 256, 0, stream>>>(hA, deg, agg, W3l, b3, W3r, h3, n);

    // ---- head ----
    head_kernel<<<(n + BT - 1) / BT, BT, 0, stream>>>(h3, W4, b4, W5, b5, out, n);
}

// Round 4
// 723.408 us; speedup vs baseline: 4.5194x; 4.5194x over previous
//
#include <hip/hip_runtime.h>

// ---------------------------------------------------------------------------
// GraphSAGE 3-layer + MLP head, fp32. N=100000, E=3200000.
// Round 4: CSR pull (R2's wave-per-node, which had TLP) + two-pass bucketed
// CSR build (kills R2's 194MB fill write-thrash). pull64 upgraded to
// 4-rows-per-instruction float4 gathers + shuffle reduce.
// R3 lesson: block-per-bucket push = 6.3k long dependent chains = latency-
// bound disaster. Aggregation wants many short chains (wave per node).
// ---------------------------------------------------------------------------

#define RB 128
#define RB_SHIFT 7
#define MAXK 1024  // supports n <= 131072

// histogram dst into rowptr (counts; scanned in-place afterwards)
__global__ void hist_kernel(const int* __restrict__ dst, int* __restrict__ deg, int E) {
    int e = blockIdx.x * blockDim.x + threadIdx.x;
    if (e < E) atomicAdd(&deg[dst[e]], 1);
}

// in-place exclusive scan, level A (1024/block). Reads complete before writes.
__global__ void scan_blocks_kernel(int* __restrict__ data, int* __restrict__ blocksum, int n) {
    __shared__ int s[256];
    int base = blockIdx.x * 1024;
    int t = threadIdx.x;
    int v[4];
    int loc = 0;
#pragma unroll
    for (int k = 0; k < 4; k++) {
        int i = base + t * 4 + k;
        v[k] = (i < n) ? data[i] : 0;
        loc += v[k];
    }
    s[t] = loc;
    __syncthreads();
    for (int off = 1; off < 256; off <<= 1) {
        int xv = (t >= off) ? s[t - off] : 0;
        __syncthreads();
        s[t] += xv;
        __syncthreads();
    }
    if (t == 255) blocksum[blockIdx.x] = s[255];
    int run = s[t] - loc;
#pragma unroll
    for (int k = 0; k < 4; k++) {
        int i = base + t * 4 + k;
        if (i < n) data[i] = run;
        run += v[k];
    }
}

__global__ void scan_sums_kernel(int* __restrict__ blocksum, int nb) {
    __shared__ int s[128];
    int t = threadIdx.x;
    int v = (t < nb) ? blocksum[t] : 0;
    s[t] = v;
    __syncthreads();
    for (int off = 1; off < 128; off <<= 1) {
        int xv = (t >= off) ? s[t - off] : 0;
        __syncthreads();
        s[t] += xv;
        __syncthreads();
    }
    if (t < nb) blocksum[t] = s[t] - v;
}

__global__ void scan_add_kernel(int* __restrict__ rowptr, const int* __restrict__ blocksum, int n) {
    int i = blockIdx.x * blockDim.x + threadIdx.x;
    if (i < n) rowptr[i] += blocksum[i >> 10];
}

__global__ void cursor_init_kernel(const int* __restrict__ rowptr, int* __restrict__ gcur, int K) {
    int b = blockIdx.x * blockDim.x + threadIdx.x;
    if (b < K) gcur[b] = rowptr[b << RB_SHIFT];
}

// Partition edges into K buckets of RB nodes, packed as src | (dst&127)<<20.
__global__ void partition_kernel(const int* __restrict__ src, const int* __restrict__ dst,
                                 int* __restrict__ gcur, unsigned* __restrict__ staging,
                                 int E, int K) {
    __shared__ int cnt[MAXK];
    __shared__ int base[MAXK];
    const int blockBase = blockIdx.x * 8192;
    for (int i = threadIdx.x; i < K; i += 512) cnt[i] = 0;
    __syncthreads();
#pragma unroll
    for (int k = 0; k < 16; k++) {
        int j = blockBase + threadIdx.x + k * 512;
        if (j < E) atomicAdd(&cnt[dst[j] >> RB_SHIFT], 1);
    }
    __syncthreads();
    for (int b = threadIdx.x; b < K; b += 512) {
        int c = cnt[b];
        base[b] = c ? atomicAdd(&gcur[b], c) : 0;
        cnt[b] = 0;
    }
    __syncthreads();
#pragma unroll
    for (int k = 0; k < 16; k++) {
        int j = blockBase + threadIdx.x + k * 512;
        if (j < E) {
            int d = dst[j];
            int b = d >> RB_SHIFT;
            int r = atomicAdd(&cnt[b], 1);
            staging[base[b] + r] = (unsigned)src[j] | ((unsigned)(d & (RB - 1)) << 20);
        }
    }
}

// scatter bucket staging into node-ordered CSR col. Writes land in the
// bucket's ~16KB window -> lines assemble in L2 (vs R2's 12.8MB random).
__global__ void bucket_fill_kernel(const unsigned* __restrict__ staging,
                                   const int* __restrict__ rowptr,
                                   int* __restrict__ col, int n, int E) {
    __shared__ int cur[RB];
    const int base_node = blockIdx.x << RB_SHIFT;
    const int beg = rowptr[base_node];
    const int end = (base_node + RB >= n) ? E : rowptr[base_node + RB];
    if (threadIdx.x < RB) {
        int node = base_node + threadIdx.x;
        cur[threadIdx.x] = (node < n) ? rowptr[node] : 0;
    }
    __syncthreads();
    for (int i = beg + threadIdx.x; i < end; i += 256) {
        unsigned v = staging[i];
        int p = atomicAdd(&cur[v >> 20], 1);
        col[p] = (int)(v & 0xFFFFF);
    }
}

// layer-1 aggregation: thread per node, float4 gather of x
__global__ void pull4_kernel(const int* __restrict__ rowptr, const int* __restrict__ col,
                             const float4* __restrict__ x, float4* __restrict__ agg,
                             int n, int E) {
    int node = blockIdx.x * blockDim.x + threadIdx.x;
    if (node >= n) return;
    int beg = rowptr[node];
    int end = (node == n - 1) ? E : rowptr[node + 1];
    float4 a = {0.f, 0.f, 0.f, 0.f};
    for (int i = beg; i < end; i++) {
        float4 v = x[col[i]];
        a.x += v.x; a.y += v.y; a.z += v.z; a.w += v.w;
    }
    agg[node] = a;
}

// F=64 aggregation: one wave per node. lane = rg*16+fg: row-group rg (0..3)
// x float4 feature-group fg (0..15). Each global_load_dwordx4 gathers 4 full
// h rows (1KB/wave-instr); unroll 2 -> 2KB in flight. xor-shuffle reduce.
__global__ void pull64_kernel(const int* __restrict__ rowptr, const int* __restrict__ col,
                              const float4* __restrict__ h4, float4* __restrict__ agg4,
                              int n, int E) {
    const int wave = threadIdx.x >> 6;
    const int lane = threadIdx.x & 63;
    const int node = blockIdx.x * 4 + wave;
    if (node >= n) return;
    const int beg = rowptr[node];
    const int end = (node == n - 1) ? E : rowptr[node + 1];
    const int fg = lane & 15;
    const int rg = lane >> 4;
    float4 acc = {0.f, 0.f, 0.f, 0.f};
    int i = beg;
    for (; i + 8 <= end; i += 8) {
        int c0 = col[i + rg];
        int c1 = col[i + 4 + rg];
        float4 v0 = h4[(size_t)c0 * 16 + fg];
        float4 v1 = h4[(size_t)c1 * 16 + fg];
        acc.x += v0.x + v1.x;
        acc.y += v0.y + v1.y;
        acc.z += v0.z + v1.z;
        acc.w += v0.w + v1.w;
    }
    for (; i + 4 <= end; i += 4) {
        int c = col[i + rg];
        float4 v = h4[(size_t)c * 16 + fg];
        acc.x += v.x; acc.y += v.y; acc.z += v.z; acc.w += v.w;
    }
    if (i < end) {
        int idx = i + rg;
        if (idx < end) {
            float4 v = h4[(size_t)col[idx] * 16 + fg];
            acc.x += v.x; acc.y += v.y; acc.z += v.z; acc.w += v.w;
        }
    }
    // reduce the 4 row-groups (lanes l, l^16, l^32, l^48)
    acc.x += __shfl_xor(acc.x, 16); acc.y += __shfl_xor(acc.y, 16);
    acc.z += __shfl_xor(acc.z, 16); acc.w += __shfl_xor(acc.w, 16);
    acc.x += __shfl_xor(acc.x, 32); acc.y += __shfl_xor(acc.y, 32);
    acc.z += __shfl_xor(acc.z, 32); acc.w += __shfl_xor(acc.w, 32);
    if (lane < 16) agg4[(size_t)node * 16 + fg] = acc;
}

// out[n][j] = relu( (agg[n]/max(deg,1)) @ Wl + b + x[n] @ Wr ), deg from rowptr
template <int FIN, int FOUT>
__global__ void sage_layer_kernel(const float* __restrict__ agg, const int* __restrict__ rowptr,
                                  const float* __restrict__ x,
                                  const float* __restrict__ Wl, const float* __restrict__ b,
                                  const float* __restrict__ Wr,
                                  float* __restrict__ out, int n, int E) {
    constexpr int NPB = 256 / FOUT;
    __shared__ float sWl[FIN * FOUT];
    __shared__ float sWr[FIN * FOUT];
    __shared__ float sb[FOUT];
    __shared__ float sA[NPB][FIN];
    __shared__ float sX[NPB][FIN];
    for (int i = threadIdx.x; i < FIN * FOUT; i += 256) {
        sWl[i] = Wl[i];
        sWr[i] = Wr[i];
    }
    if (threadIdx.x < FOUT) sb[threadIdx.x] = b[threadIdx.x];
    const int first = blockIdx.x * NPB;
    for (int i = threadIdx.x; i < NPB * FIN; i += 256) {
        int local = i / FIN, k = i % FIN;
        int node = first + local;
        float av = 0.f, xv = 0.f;
        if (node < n) {
            av = agg[(size_t)node * FIN + k];
            xv = x[(size_t)node * FIN + k];
        }
        sA[local][k] = av;
        sX[local][k] = xv;
    }
    __syncthreads();

    const int local = threadIdx.x / FOUT;
    const int j = threadIdx.x % FOUT;
    const int node = first + local;
    if (node >= n) return;
    const int beg = rowptr[node];
    const int end = (node == n - 1) ? E : rowptr[node + 1];
    const float inv = 1.0f / (float)max(end - beg, 1);
    float accA = 0.f, accX = 0.f;
#pragma unroll
    for (int k = 0; k < FIN; k++) {
        accA += sA[local][k] * sWl[k * FOUT + j];
        accX += sX[local][k] * sWr[k * FOUT + j];
    }
    out[(size_t)node * FOUT + j] = fmaxf(sb[j] + inv * accA + accX, 0.0f);
}

__global__ void head_kernel(const float* __restrict__ h3, const float* __restrict__ W4,
                            const float* __restrict__ b4, const float* __restrict__ W5,
                            const float* __restrict__ b5, float* __restrict__ out, int n) {
    __shared__ float sW4[32 * 16];
    __shared__ float sb4[16];
    __shared__ float sW5[16];
    for (int i = threadIdx.x; i < 32 * 16; i += blockDim.x) sW4[i] = W4[i];
    if (threadIdx.x < 16) {
        sb4[threadIdx.x] = b4[threadIdx.x];
        sW5[threadIdx.x] = W5[threadIdx.x];
    }
    __syncthreads();

    int node = blockIdx.x * blockDim.x + threadIdx.x;
    if (node >= n) return;

    float hl[32];
#pragma unroll
    for (int k = 0; k < 32; k++) hl[k] = h3[(size_t)node * 32 + k];

    float acc = b5[0];
#pragma unroll
    for (int j = 0; j < 16; j++) {
        float t = sb4[j];
#pragma unroll
        for (int k = 0; k < 32; k++) t += hl[k] * sW4[k * 16 + j];
        acc += fmaxf(t, 0.0f) * sW5[j];
    }
    out[node] = acc;
}

extern "C" void kernel_launch(void* const* d_in, const int* in_sizes, int n_in,
                              void* d_out, int out_size, void* d_ws, size_t ws_size,
                              hipStream_t stream) {
    const float* x   = (const float*)d_in[0];
    const int*   ei  = (const int*)d_in[1];
    const float* W1l = (const float*)d_in[2];
    const float* b1  = (const float*)d_in[3];
    const float* W1r = (const float*)d_in[4];
    const float* W2l = (const float*)d_in[5];
    const float* b2  = (const float*)d_in[6];
    const float* W2r = (const float*)d_in[7];
    const float* W3l = (const float*)d_in[8];
    const float* b3  = (const float*)d_in[9];
    const float* W3r = (const float*)d_in[10];
    const float* W4  = (const float*)d_in[11];
    const float* b4  = (const float*)d_in[12];
    const float* W5  = (const float*)d_in[13];
    const float* b5  = (const float*)d_in[14];
    float* out = (float*)d_out;

    const int n = in_sizes[0] / 4;
    const int E = in_sizes[1] / 2;
    const int* src = ei;
    const int* dst = ei + E;
    const int K = (n + RB - 1) >> RB_SHIFT;  // 782

    char* ws = (char*)d_ws;
    size_t off = 0;
    auto alloc = [&](size_t bytes) {
        char* p = ws + off;
        off += (bytes + 255) & ~(size_t)255;
        return p;
    };
    int*      rowptr  = (int*)alloc(((size_t)n) * sizeof(int));
    int*      gcur    = (int*)alloc((size_t)K * sizeof(int));
    int*      bsum    = (int*)alloc(128 * sizeof(int));
    unsigned* staging = (unsigned*)alloc((size_t)E * sizeof(unsigned));  // 12.8MB; reused for h3
    int*      col     = (int*)alloc((size_t)E * sizeof(int));            // 12.8MB
    float*    agg     = (float*)alloc((size_t)n * 64 * sizeof(float));
    float*    hA      = (float*)alloc((size_t)n * 64 * sizeof(float));
    float*    agg4    = agg;  // layer-1 agg aliases agg (dead at that point)
    (void)ws_size;

    const int BT = 256;
    const int nb = (n + 1023) / 1024;  // 98 <= 128

    // ---- rowptr (hist -> in-place scan) + bucketed partition + CSR fill ----
    hipMemsetAsync(rowptr, 0, (size_t)n * sizeof(int), stream);
    hist_kernel<<<(E + BT - 1) / BT, BT, 0, stream>>>(dst, rowptr, E);
    scan_blocks_kernel<<<nb, 256, 0, stream>>>(rowptr, bsum, n);
    scan_sums_kernel<<<1, 128, 0, stream>>>(bsum, nb);
    scan_add_kernel<<<(n + BT - 1) / BT, BT, 0, stream>>>(rowptr, bsum, n);
    cursor_init_kernel<<<(K + BT - 1) / BT, BT, 0, stream>>>(rowptr, gcur, K);
    partition_kernel<<<(E + 8191) / 8192, 512, 0, stream>>>(src, dst, gcur, staging, E, K);
    bucket_fill_kernel<<<K, 256, 0, stream>>>(staging, rowptr, col, n, E);

    // ---- layer 1: x[N,4] -> hA[N,64] ----
    pull4_kernel<<<(n + BT - 1) / BT, BT, 0, stream>>>(rowptr, col, (const float4*)x,
                                                       (float4*)agg4, n, E);
    sage_layer_kernel<4, 64><<<(n + 3) / 4, 256, 0, stream>>>(agg4, rowptr, x, W1l, b1, W1r,
                                                              hA, n, E);

    // ---- layer 2: hA -> h2 (in-place into agg) ----
    pull64_kernel<<<(n + 3) / 4, 256, 0, stream>>>(rowptr, col, (const float4*)hA,
                                                   (float4*)agg, n, E);
    sage_layer_kernel<64, 64><<<(n + 3) / 4, 256, 0, stream>>>(agg, rowptr, hA, W2l, b2, W2r,
                                                               agg, n, E);

    // ---- layer 3: h2=agg -> h3 (into staging; staging dead after fill) ----
    pull64_kernel<<<(n + 3) / 4, 256, 0, stream>>>(rowptr, col, (const float4*)agg,
                                                   (float4*)hA, n, E);
    float* h3 = (float*)staging;  // N*32 floats == E uints == 12.8MB
    sage_layer_kernel<64, 32><<<(n + 7) / 8, 256, 0, stream>>>(hA, rowptr, agg, W3l, b3, W3r,
                                                               h3, n, E);

    // ---- head ----
    head_kernel<<<(n + BT - 1) / BT, BT, 0, stream>>>(h3, W4, b4, W5, b5, out, n);
}

// Round 5
// 482.963 us; speedup vs baseline: 6.7694x; 1.4979x over previous
//
#include <hip/hip_runtime.h>

// ---------------------------------------------------------------------------
// GraphSAGE 3-layer + MLP head, fp32. N=100000, E=3200000.
// Round 5:
//  - CSR build without any global fine-grained histogram (R4's hist wrote
//    ~100MB: 3.2M device atomics thrash lines across 8 XCD L2s). Two-level
//    counting sort: bucket_count (LDS hist, 1 atomic/block/bucket on 3KB)
//    -> bscan -> partition -> bucket_build (LDS hist+scan per 16KB bucket,
//    emits rowptr + node-sorted col in one pass).
//  - pull64 gathers fp16 rows (128B) written as mirrors by the sage layers:
//    half gather bytes, 8 rows per dwordx4 instruction. fp32 accumulate.
//  - aliases: h16 = staging (dead after build), h3 = col (dead after pull3).
// ---------------------------------------------------------------------------

#define RB 128
#define RB_SHIFT 7
#define MAXK 1024  // supports n <= 131072

typedef _Float16 f16;

// ---- CSR build ------------------------------------------------------------

__global__ void bucket_count_kernel(const int* __restrict__ dst, int* __restrict__ bcnt,
                                    int E, int K) {
    __shared__ int cnt[MAXK];
    for (int i = threadIdx.x; i < K; i += 512) cnt[i] = 0;
    __syncthreads();
    const int base = blockIdx.x * 8192;
#pragma unroll
    for (int k = 0; k < 16; k++) {
        int j = base + threadIdx.x + k * 512;
        if (j < E) atomicAdd(&cnt[dst[j] >> RB_SHIFT], 1);
    }
    __syncthreads();
    for (int i = threadIdx.x; i < K; i += 512)
        if (cnt[i]) atomicAdd(&bcnt[i], cnt[i]);
}

// single-block exclusive scan of K bucket sizes (K <= 1024)
__global__ void bscan_kernel(const int* __restrict__ bcnt, int* __restrict__ bbase,
                             int* __restrict__ gcur, int K, int E) {
    __shared__ int s[1024];
    const int t = threadIdx.x;
    int v = (t < K) ? bcnt[t] : 0;
    s[t] = v;
    __syncthreads();
    for (int off = 1; off < 1024; off <<= 1) {
        int xv = (t >= off) ? s[t - off] : 0;
        __syncthreads();
        s[t] += xv;
        __syncthreads();
    }
    if (t < K) {
        int ex = s[t] - v;
        bbase[t] = ex;
        gcur[t] = ex;
    }
    if (t == 0) bbase[K] = E;
}

// partition edges into K buckets of RB nodes, packed src | (dst&127)<<20
__global__ void partition_kernel(const int* __restrict__ src, const int* __restrict__ dst,
                                 int* __restrict__ gcur, unsigned* __restrict__ staging,
                                 int E, int K) {
    __shared__ int cnt[MAXK];
    __shared__ int base[MAXK];
    const int blockBase = blockIdx.x * 8192;
    for (int i = threadIdx.x; i < K; i += 512) cnt[i] = 0;
    __syncthreads();
#pragma unroll
    for (int k = 0; k < 16; k++) {
        int j = blockBase + threadIdx.x + k * 512;
        if (j < E) atomicAdd(&cnt[dst[j] >> RB_SHIFT], 1);
    }
    __syncthreads();
    for (int b = threadIdx.x; b < K; b += 512) {
        int c = cnt[b];
        base[b] = c ? atomicAdd(&gcur[b], c) : 0;
        cnt[b] = 0;
    }
    __syncthreads();
#pragma unroll
    for (int k = 0; k < 16; k++) {
        int j = blockBase + threadIdx.x + k * 512;
        if (j < E) {
            int d = dst[j];
            int b = d >> RB_SHIFT;
            int r = atomicAdd(&cnt[b], 1);
            staging[base[b] + r] = (unsigned)src[j] | ((unsigned)(d & (RB - 1)) << 20);
        }
    }
}

// per-bucket: LDS node hist + scan -> rowptr, then node-sorted col scatter
// (writes land in the bucket's contiguous ~16KB window)
__global__ void bucket_build_kernel(const unsigned* __restrict__ staging,
                                    const int* __restrict__ bbase,
                                    int* __restrict__ rowptr, int* __restrict__ col,
                                    int n, int K) {
    __shared__ int cnt[RB];
    __shared__ int cur[RB];
    const int b = blockIdx.x;
    const int beg = bbase[b];
    const int end = bbase[b + 1];
    const int t = threadIdx.x;
    if (t < RB) cnt[t] = 0;
    __syncthreads();
    for (int i = beg + t; i < end; i += 256) atomicAdd(&cnt[staging[i] >> 20], 1);
    __syncthreads();
    int v = (t < RB) ? cnt[t] : 0;
    for (int off = 1; off < RB; off <<= 1) {
        int xv = (t < RB && t >= off) ? cnt[t - off] : 0;
        __syncthreads();
        if (t < RB) cnt[t] += xv;
        __syncthreads();
    }
    if (t < RB) {
        int ex = beg + cnt[t] - v;  // exclusive prefix
        int node = (b << RB_SHIFT) + t;
        if (node < n) rowptr[node] = ex;
        cur[t] = ex;
    }
    __syncthreads();
    for (int i = beg + t; i < end; i += 256) {
        unsigned s = staging[i];
        int p = atomicAdd(&cur[s >> 20], 1);
        col[p] = (int)(s & 0xFFFFF);
    }
}

// ---- aggregation ----------------------------------------------------------

__global__ void pull4_kernel(const int* __restrict__ rowptr, const int* __restrict__ col,
                             const float4* __restrict__ x, float4* __restrict__ agg,
                             int n, int E) {
    int node = blockIdx.x * blockDim.x + threadIdx.x;
    if (node >= n) return;
    int beg = rowptr[node];
    int end = (node == n - 1) ? E : rowptr[node + 1];
    float4 a = {0.f, 0.f, 0.f, 0.f};
    for (int i = beg; i < end; i++) {
        float4 v = x[col[i]];
        a.x += v.x; a.y += v.y; a.z += v.z; a.w += v.w;
    }
    agg[node] = a;
}

// F=64 fp16 aggregation: wave per node. lane = rg*8+fg: row-group rg (0..7)
// x 16B chunk fg (0..7). One dwordx4 = 8 half-rows (1KB/wave-instr).
// fp32 accumulate, xor-shuffle reduce over rg, fp32 output.
__global__ void pull64h_kernel(const int* __restrict__ rowptr, const int* __restrict__ col,
                               const uint4* __restrict__ h16, float4* __restrict__ agg4,
                               int n, int E) {
    const int wave = threadIdx.x >> 6;
    const int lane = threadIdx.x & 63;
    const int node = blockIdx.x * 4 + wave;
    if (node >= n) return;
    const int beg = rowptr[node];
    const int end = (node == n - 1) ? E : rowptr[node + 1];
    const int fg = lane & 7;
    const int rg = lane >> 3;
    float acc[8] = {0.f, 0.f, 0.f, 0.f, 0.f, 0.f, 0.f, 0.f};
    int i = beg;
    for (; i + 16 <= end; i += 16) {
        int c0 = col[i + rg];
        int c1 = col[i + 8 + rg];
        uint4 u0 = h16[(size_t)c0 * 8 + fg];
        uint4 u1 = h16[(size_t)c1 * 8 + fg];
        const f16* p0 = (const f16*)&u0;
        const f16* p1 = (const f16*)&u1;
#pragma unroll
        for (int k = 0; k < 8; k++) acc[k] += (float)p0[k] + (float)p1[k];
    }
    for (; i < end; i += 8) {
        int idx = i + rg;
        if (idx < end) {
            uint4 u = h16[(size_t)col[idx] * 8 + fg];
            const f16* p = (const f16*)&u;
#pragma unroll
            for (int k = 0; k < 8; k++) acc[k] += (float)p[k];
        }
    }
#pragma unroll
    for (int k = 0; k < 8; k++) {
        acc[k] += __shfl_xor(acc[k], 8);
        acc[k] += __shfl_xor(acc[k], 16);
        acc[k] += __shfl_xor(acc[k], 32);
    }
    if (rg == 0) {
        // lane fg holds features [fg*8, fg*8+8)
        float4 lo = {acc[0], acc[1], acc[2], acc[3]};
        float4 hi = {acc[4], acc[5], acc[6], acc[7]};
        agg4[(size_t)node * 16 + fg * 2] = lo;
        agg4[(size_t)node * 16 + fg * 2 + 1] = hi;
    }
}

// ---- dense layers ---------------------------------------------------------

// out[n][j] = relu( (agg[n]/max(deg,1)) @ Wl + b + x[n] @ Wr ); optional fp16 mirror
template <int FIN, int FOUT>
__global__ void sage_layer_kernel(const float* __restrict__ agg, const int* __restrict__ rowptr,
                                  const float* __restrict__ x,
                                  const float* __restrict__ Wl, const float* __restrict__ b,
                                  const float* __restrict__ Wr,
                                  float* __restrict__ out, f16* __restrict__ out16,
                                  int n, int E) {
    constexpr int NPB = 256 / FOUT;
    __shared__ float sWl[FIN * FOUT];
    __shared__ float sWr[FIN * FOUT];
    __shared__ float sb[FOUT];
    __shared__ float sA[NPB][FIN];
    __shared__ float sX[NPB][FIN];
    for (int i = threadIdx.x; i < FIN * FOUT; i += 256) {
        sWl[i] = Wl[i];
        sWr[i] = Wr[i];
    }
    if (threadIdx.x < FOUT) sb[threadIdx.x] = b[threadIdx.x];
    const int first = blockIdx.x * NPB;
    for (int i = threadIdx.x; i < NPB * FIN; i += 256) {
        int local = i / FIN, k = i % FIN;
        int node = first + local;
        float av = 0.f, xv = 0.f;
        if (node < n) {
            av = agg[(size_t)node * FIN + k];
            xv = x[(size_t)node * FIN + k];
        }
        sA[local][k] = av;
        sX[local][k] = xv;
    }
    __syncthreads();

    const int local = threadIdx.x / FOUT;
    const int j = threadIdx.x % FOUT;
    const int node = first + local;
    if (node >= n) return;
    const int beg = rowptr[node];
    const int end = (node == n - 1) ? E : rowptr[node + 1];
    const float inv = 1.0f / (float)max(end - beg, 1);
    float accA = 0.f, accX = 0.f;
#pragma unroll
    for (int k = 0; k < FIN; k++) {
        accA += sA[local][k] * sWl[k * FOUT + j];
        accX += sX[local][k] * sWr[k * FOUT + j];
    }
    float r = fmaxf(sb[j] + inv * accA + accX, 0.0f);
    out[(size_t)node * FOUT + j] = r;
    if (out16) out16[(size_t)node * FOUT + j] = (f16)r;
}

__global__ void head_kernel(const float* __restrict__ h3, const float* __restrict__ W4,
                            const float* __restrict__ b4, const float* __restrict__ W5,
                            const float* __restrict__ b5, float* __restrict__ out, int n) {
    __shared__ float sW4[32 * 16];
    __shared__ float sb4[16];
    __shared__ float sW5[16];
    for (int i = threadIdx.x; i < 32 * 16; i += blockDim.x) sW4[i] = W4[i];
    if (threadIdx.x < 16) {
        sb4[threadIdx.x] = b4[threadIdx.x];
        sW5[threadIdx.x] = W5[threadIdx.x];
    }
    __syncthreads();

    int node = blockIdx.x * blockDim.x + threadIdx.x;
    if (node >= n) return;

    float hl[32];
#pragma unroll
    for (int k = 0; k < 32; k++) hl[k] = h3[(size_t)node * 32 + k];

    float acc = b5[0];
#pragma unroll
    for (int j = 0; j < 16; j++) {
        float t = sb4[j];
#pragma unroll
        for (int k = 0; k < 32; k++) t += hl[k] * sW4[k * 16 + j];
        acc += fmaxf(t, 0.0f) * sW5[j];
    }
    out[node] = acc;
}

// ---- launch ---------------------------------------------------------------

extern "C" void kernel_launch(void* const* d_in, const int* in_sizes, int n_in,
                              void* d_out, int out_size, void* d_ws, size_t ws_size,
                              hipStream_t stream) {
    const float* x   = (const float*)d_in[0];
    const int*   ei  = (const int*)d_in[1];
    const float* W1l = (const float*)d_in[2];
    const float* b1  = (const float*)d_in[3];
    const float* W1r = (const float*)d_in[4];
    const float* W2l = (const float*)d_in[5];
    const float* b2  = (const float*)d_in[6];
    const float* W2r = (const float*)d_in[7];
    const float* W3l = (const float*)d_in[8];
    const float* b3  = (const float*)d_in[9];
    const float* W3r = (const float*)d_in[10];
    const float* W4  = (const float*)d_in[11];
    const float* b4  = (const float*)d_in[12];
    const float* W5  = (const float*)d_in[13];
    const float* b5  = (const float*)d_in[14];
    float* out = (float*)d_out;

    const int n = in_sizes[0] / 4;
    const int E = in_sizes[1] / 2;
    const int* src = ei;
    const int* dst = ei + E;
    const int K = (n + RB - 1) >> RB_SHIFT;  // 782

    char* ws = (char*)d_ws;
    size_t off = 0;
    auto alloc = [&](size_t bytes) {
        char* p = ws + off;
        off += (bytes + 255) & ~(size_t)255;
        return p;
    };
    int*      rowptr  = (int*)alloc((size_t)n * sizeof(int));
    int*      bcnt    = (int*)alloc((size_t)(K + 1) * sizeof(int));
    int*      bbase   = (int*)alloc((size_t)(K + 1) * sizeof(int));
    int*      gcur    = (int*)alloc((size_t)K * sizeof(int));
    unsigned* staging = (unsigned*)alloc((size_t)E * sizeof(unsigned));  // 12.8MB; -> h16
    int*      col     = (int*)alloc((size_t)E * sizeof(int));            // 12.8MB; -> h3
    float*    agg     = (float*)alloc((size_t)n * 64 * sizeof(float));
    float*    hA      = (float*)alloc((size_t)n * 64 * sizeof(float));
    float*    agg4    = agg;            // layer-1 agg aliases agg
    f16*      h16     = (f16*)staging;  // fp16 mirror reuses staging after build
    (void)ws_size;

    const int BT = 256;
    const int EB = (E + 8191) / 8192;  // 391

    // ---- CSR build (no global fine-grained histogram) ----
    hipMemsetAsync(bcnt, 0, (size_t)(K + 1) * sizeof(int), stream);
    bucket_count_kernel<<<EB, 512, 0, stream>>>(dst, bcnt, E, K);
    bscan_kernel<<<1, 1024, 0, stream>>>(bcnt, bbase, gcur, K, E);
    partition_kernel<<<EB, 512, 0, stream>>>(src, dst, gcur, staging, E, K);
    bucket_build_kernel<<<K, 256, 0, stream>>>(staging, bbase, rowptr, col, n, K);

    // ---- layer 1: x[N,4] -> hA[N,64] (+h16 mirror) ----
    pull4_kernel<<<(n + BT - 1) / BT, BT, 0, stream>>>(rowptr, col, (const float4*)x,
                                                       (float4*)agg4, n, E);
    sage_layer_kernel<4, 64><<<(n + 3) / 4, 256, 0, stream>>>(agg4, rowptr, x, W1l, b1, W1r,
                                                              hA, h16, n, E);

    // ---- layer 2: h1_16 -> agg; sage -> agg fp32 (+h2_16 mirror) ----
    pull64h_kernel<<<(n + 3) / 4, 256, 0, stream>>>(rowptr, col, (const uint4*)h16,
                                                    (float4*)agg, n, E);
    sage_layer_kernel<64, 64><<<(n + 3) / 4, 256, 0, stream>>>(agg, rowptr, hA, W2l, b2, W2r,
                                                               agg, h16, n, E);

    // ---- layer 3: h2_16 -> hA; sage -> h3 (= col buffer, dead after pull) ----
    pull64h_kernel<<<(n + 3) / 4, 256, 0, stream>>>(rowptr, col, (const uint4*)h16,
                                                    (float4*)hA, n, E);
    float* h3 = (float*)col;
    sage_layer_kernel<64, 32><<<(n + 7) / 8, 256, 0, stream>>>(hA, rowptr, agg, W3l, b3, W3r,
                                                               h3, (f16*)nullptr, n, E);

    // ---- head ----
    head_kernel<<<(n + BT - 1) / BT, BT, 0, stream>>>(h3, W4, b4, W5, b5, out, n);
}

// Round 6
// 437.846 us; speedup vs baseline: 7.4670x; 1.1030x over previous
//
#include <hip/hip_runtime.h>

// ---------------------------------------------------------------------------
// GraphSAGE 3-layer + MLP head, fp32. N=100000, E=3200000.
// Round 6: register-tiled fused sage GEMM (R5's sage was LDS-read bound:
// 4 ds_read_b32 per 2 FMAs, 108us). Now: merged K=2*FIN loop over [mean|x]
// @ [Wl;Wr], transposed weights in LDS, 4-node x TJ-output register tile,
// stride-16 tiling + row pad 4 -> 2-way bank aliasing (free). Pull kernels
// emit mean (divide by deg at writeback) so the GEMM has no per-node scale.
// ---------------------------------------------------------------------------

#define RB 128
#define RB_SHIFT 7
#define MAXK 1024  // supports n <= 131072

typedef _Float16 f16;

// ---- CSR build ------------------------------------------------------------

__global__ void bucket_count_kernel(const int* __restrict__ dst, int* __restrict__ bcnt,
                                    int E, int K) {
    __shared__ int cnt[MAXK];
    for (int i = threadIdx.x; i < K; i += 512) cnt[i] = 0;
    __syncthreads();
    const int base = blockIdx.x * 8192;
#pragma unroll
    for (int k = 0; k < 16; k++) {
        int j = base + threadIdx.x + k * 512;
        if (j < E) atomicAdd(&cnt[dst[j] >> RB_SHIFT], 1);
    }
    __syncthreads();
    for (int i = threadIdx.x; i < K; i += 512)
        if (cnt[i]) atomicAdd(&bcnt[i], cnt[i]);
}

__global__ void bscan_kernel(const int* __restrict__ bcnt, int* __restrict__ bbase,
                             int* __restrict__ gcur, int K, int E) {
    __shared__ int s[1024];
    const int t = threadIdx.x;
    int v = (t < K) ? bcnt[t] : 0;
    s[t] = v;
    __syncthreads();
    for (int off = 1; off < 1024; off <<= 1) {
        int xv = (t >= off) ? s[t - off] : 0;
        __syncthreads();
        s[t] += xv;
        __syncthreads();
    }
    if (t < K) {
        int ex = s[t] - v;
        bbase[t] = ex;
        gcur[t] = ex;
    }
    if (t == 0) bbase[K] = E;
}

__global__ void partition_kernel(const int* __restrict__ src, const int* __restrict__ dst,
                                 int* __restrict__ gcur, unsigned* __restrict__ staging,
                                 int E, int K) {
    __shared__ int cnt[MAXK];
    __shared__ int base[MAXK];
    const int blockBase = blockIdx.x * 8192;
    for (int i = threadIdx.x; i < K; i += 512) cnt[i] = 0;
    __syncthreads();
#pragma unroll
    for (int k = 0; k < 16; k++) {
        int j = blockBase + threadIdx.x + k * 512;
        if (j < E) atomicAdd(&cnt[dst[j] >> RB_SHIFT], 1);
    }
    __syncthreads();
    for (int b = threadIdx.x; b < K; b += 512) {
        int c = cnt[b];
        base[b] = c ? atomicAdd(&gcur[b], c) : 0;
        cnt[b] = 0;
    }
    __syncthreads();
#pragma unroll
    for (int k = 0; k < 16; k++) {
        int j = blockBase + threadIdx.x + k * 512;
        if (j < E) {
            int d = dst[j];
            int b = d >> RB_SHIFT;
            int r = atomicAdd(&cnt[b], 1);
            staging[base[b] + r] = (unsigned)src[j] | ((unsigned)(d & (RB - 1)) << 20);
        }
    }
}

__global__ void bucket_build_kernel(const unsigned* __restrict__ staging,
                                    const int* __restrict__ bbase,
                                    int* __restrict__ rowptr, int* __restrict__ col,
                                    int n, int K) {
    __shared__ int cnt[RB];
    __shared__ int cur[RB];
    const int b = blockIdx.x;
    const int beg = bbase[b];
    const int end = bbase[b + 1];
    const int t = threadIdx.x;
    if (t < RB) cnt[t] = 0;
    __syncthreads();
    for (int i = beg + t; i < end; i += 256) atomicAdd(&cnt[staging[i] >> 20], 1);
    __syncthreads();
    int v = (t < RB) ? cnt[t] : 0;
    for (int off = 1; off < RB; off <<= 1) {
        int xv = (t < RB && t >= off) ? cnt[t - off] : 0;
        __syncthreads();
        if (t < RB) cnt[t] += xv;
        __syncthreads();
    }
    if (t < RB) {
        int ex = beg + cnt[t] - v;
        int node = (b << RB_SHIFT) + t;
        if (node < n) rowptr[node] = ex;
        cur[t] = ex;
    }
    __syncthreads();
    for (int i = beg + t; i < end; i += 256) {
        unsigned s = staging[i];
        int p = atomicAdd(&cur[s >> 20], 1);
        col[p] = (int)(s & 0xFFFFF);
    }
}

// ---- aggregation (emits MEAN, not sum) ------------------------------------

__global__ void pull4_kernel(const int* __restrict__ rowptr, const int* __restrict__ col,
                             const float4* __restrict__ x, float4* __restrict__ mean,
                             int n, int E) {
    int node = blockIdx.x * blockDim.x + threadIdx.x;
    if (node >= n) return;
    int beg = rowptr[node];
    int end = (node == n - 1) ? E : rowptr[node + 1];
    float4 a = {0.f, 0.f, 0.f, 0.f};
    for (int i = beg; i < end; i++) {
        float4 v = x[col[i]];
        a.x += v.x; a.y += v.y; a.z += v.z; a.w += v.w;
    }
    float inv = 1.0f / (float)max(end - beg, 1);
    a.x *= inv; a.y *= inv; a.z *= inv; a.w *= inv;
    mean[node] = a;
}

// F=64 fp16 aggregation: wave per node. lane = rg*8+fg. 8 half-rows per
// dwordx4. fp32 accumulate, shuffle reduce, divide by deg, fp32 mean out.
__global__ void pull64h_kernel(const int* __restrict__ rowptr, const int* __restrict__ col,
                               const uint4* __restrict__ h16, float4* __restrict__ mean4,
                               int n, int E) {
    const int wave = threadIdx.x >> 6;
    const int lane = threadIdx.x & 63;
    const int node = blockIdx.x * 4 + wave;
    if (node >= n) return;
    const int beg = rowptr[node];
    const int end = (node == n - 1) ? E : rowptr[node + 1];
    const int fg = lane & 7;
    const int rg = lane >> 3;
    float acc[8] = {0.f, 0.f, 0.f, 0.f, 0.f, 0.f, 0.f, 0.f};
    int i = beg;
    for (; i + 16 <= end; i += 16) {
        int c0 = col[i + rg];
        int c1 = col[i + 8 + rg];
        uint4 u0 = h16[(size_t)c0 * 8 + fg];
        uint4 u1 = h16[(size_t)c1 * 8 + fg];
        const f16* p0 = (const f16*)&u0;
        const f16* p1 = (const f16*)&u1;
#pragma unroll
        for (int k = 0; k < 8; k++) acc[k] += (float)p0[k] + (float)p1[k];
    }
    for (; i < end; i += 8) {
        int idx = i + rg;
        if (idx < end) {
            uint4 u = h16[(size_t)col[idx] * 8 + fg];
            const f16* p = (const f16*)&u;
#pragma unroll
            for (int k = 0; k < 8; k++) acc[k] += (float)p[k];
        }
    }
#pragma unroll
    for (int k = 0; k < 8; k++) {
        acc[k] += __shfl_xor(acc[k], 8);
        acc[k] += __shfl_xor(acc[k], 16);
        acc[k] += __shfl_xor(acc[k], 32);
    }
    if (rg == 0) {
        float inv = 1.0f / (float)max(end - beg, 1);
        float4 lo = {acc[0] * inv, acc[1] * inv, acc[2] * inv, acc[3] * inv};
        float4 hi = {acc[4] * inv, acc[5] * inv, acc[6] * inv, acc[7] * inv};
        mean4[(size_t)node * 16 + fg * 2] = lo;
        mean4[(size_t)node * 16 + fg * 2 + 1] = hi;
    }
}

// ---- dense layers: register-tiled GEMM ------------------------------------
// out[node][j] = relu( b[j] + sum_{k<2FIN} C[node][k] * W[k][j] ),
// C = [mean | x], W = [Wl ; Wr] (transposed in LDS).
// Block = 256 threads = 16(tx) x 16(ty); handles 64 nodes.
// Thread tile: nodes {tx + 16*i}, outputs {ty + 16*jj}  (stride-16: bank-safe)
template <int FIN, int FOUT>
__global__ __launch_bounds__(256) void sage_gemm_kernel(
    const float* __restrict__ mean, const float* __restrict__ x,
    const float* __restrict__ Wl, const float* __restrict__ b,
    const float* __restrict__ Wr,
    float* __restrict__ out, f16* __restrict__ out16, int n) {
    constexpr int K2 = 2 * FIN;
    constexpr int RW = K2 + 4;       // padded row length (floats), 16B-aligned
    constexpr int TJ = FOUT / 16;    // outputs per thread
    constexpr int F4 = FIN / 4;      // float4 per half-row
    __shared__ float sC[64 * RW];
    __shared__ float sW[FOUT * RW];
    __shared__ float sb[FOUT];
    const int first = blockIdx.x * 64;

    // stage transposed weights: sW[j][kk] = Wl[kk][j]; sW[j][FIN+kk] = Wr[kk][j]
    for (int i = threadIdx.x; i < FIN * FOUT; i += 256) {
        int kk = i / FOUT, j = i % FOUT;  // coalesced global reads
        sW[j * RW + kk] = Wl[kk * FOUT + j];
        sW[j * RW + FIN + kk] = Wr[kk * FOUT + j];
    }
    if (threadIdx.x < FOUT) sb[threadIdx.x] = b[threadIdx.x];

    // stage activations: sC[node][0..FIN) = mean row, [FIN..2FIN) = x row
    for (int i = threadIdx.x; i < 64 * F4; i += 256) {
        int node = i / F4, g = i % F4;
        int gn = first + node;
        float4 mv = {0.f, 0.f, 0.f, 0.f}, xv = {0.f, 0.f, 0.f, 0.f};
        if (gn < n) {
            mv = ((const float4*)mean)[(size_t)gn * F4 + g];
            xv = ((const float4*)x)[(size_t)gn * F4 + g];
        }
        *(float4*)&sC[node * RW + 4 * g] = mv;
        *(float4*)&sC[node * RW + FIN + 4 * g] = xv;
    }
    __syncthreads();

    const int tx = threadIdx.x & 15;
    const int ty = threadIdx.x >> 4;
    float acc[4][TJ];
#pragma unroll
    for (int i = 0; i < 4; i++)
#pragma unroll
        for (int jj = 0; jj < TJ; jj++) acc[i][jj] = 0.f;

    for (int k4 = 0; k4 < K2; k4 += 4) {
        float4 a[4], w[TJ];
#pragma unroll
        for (int i = 0; i < 4; i++) a[i] = *(const float4*)&sC[(tx + 16 * i) * RW + k4];
#pragma unroll
        for (int jj = 0; jj < TJ; jj++) w[jj] = *(const float4*)&sW[(ty + 16 * jj) * RW + k4];
#pragma unroll
        for (int i = 0; i < 4; i++)
#pragma unroll
            for (int jj = 0; jj < TJ; jj++) {
                acc[i][jj] += a[i].x * w[jj].x + a[i].y * w[jj].y +
                              a[i].z * w[jj].z + a[i].w * w[jj].w;
            }
    }

#pragma unroll
    for (int i = 0; i < 4; i++) {
        int node = first + tx + 16 * i;
        if (node >= n) continue;
#pragma unroll
        for (int jj = 0; jj < TJ; jj++) {
            int j = ty + 16 * jj;
            float r = fmaxf(acc[i][jj] + sb[j], 0.0f);
            out[(size_t)node * FOUT + j] = r;
            if (out16) out16[(size_t)node * FOUT + j] = (f16)r;
        }
    }
}

__global__ void head_kernel(const float* __restrict__ h3, const float* __restrict__ W4,
                            const float* __restrict__ b4, const float* __restrict__ W5,
                            const float* __restrict__ b5, float* __restrict__ out, int n) {
    __shared__ float sW4[32 * 16];
    __shared__ float sb4[16];
    __shared__ float sW5[16];
    for (int i = threadIdx.x; i < 32 * 16; i += blockDim.x) sW4[i] = W4[i];
    if (threadIdx.x < 16) {
        sb4[threadIdx.x] = b4[threadIdx.x];
        sW5[threadIdx.x] = W5[threadIdx.x];
    }
    __syncthreads();

    int node = blockIdx.x * blockDim.x + threadIdx.x;
    if (node >= n) return;

    float hl[32];
#pragma unroll
    for (int k = 0; k < 32; k++) hl[k] = h3[(size_t)node * 32 + k];

    float acc = b5[0];
#pragma unroll
    for (int j = 0; j < 16; j++) {
        float t = sb4[j];
#pragma unroll
        for (int k = 0; k < 32; k++) t += hl[k] * sW4[k * 16 + j];
        acc += fmaxf(t, 0.0f) * sW5[j];
    }
    out[node] = acc;
}

// ---- launch ---------------------------------------------------------------

extern "C" void kernel_launch(void* const* d_in, const int* in_sizes, int n_in,
                              void* d_out, int out_size, void* d_ws, size_t ws_size,
                              hipStream_t stream) {
    const float* x   = (const float*)d_in[0];
    const int*   ei  = (const int*)d_in[1];
    const float* W1l = (const float*)d_in[2];
    const float* b1  = (const float*)d_in[3];
    const float* W1r = (const float*)d_in[4];
    const float* W2l = (const float*)d_in[5];
    const float* b2  = (const float*)d_in[6];
    const float* W2r = (const float*)d_in[7];
    const float* W3l = (const float*)d_in[8];
    const float* b3  = (const float*)d_in[9];
    const float* W3r = (const float*)d_in[10];
    const float* W4  = (const float*)d_in[11];
    const float* b4  = (const float*)d_in[12];
    const float* W5  = (const float*)d_in[13];
    const float* b5  = (const float*)d_in[14];
    float* out = (float*)d_out;

    const int n = in_sizes[0] / 4;
    const int E = in_sizes[1] / 2;
    const int* src = ei;
    const int* dst = ei + E;
    const int K = (n + RB - 1) >> RB_SHIFT;  // 782

    char* ws = (char*)d_ws;
    size_t off = 0;
    auto alloc = [&](size_t bytes) {
        char* p = ws + off;
        off += (bytes + 255) & ~(size_t)255;
        return p;
    };
    int*      rowptr  = (int*)alloc((size_t)n * sizeof(int));
    int*      bcnt    = (int*)alloc((size_t)(K + 1) * sizeof(int));
    int*      bbase   = (int*)alloc((size_t)(K + 1) * sizeof(int));
    int*      gcur    = (int*)alloc((size_t)K * sizeof(int));
    unsigned* staging = (unsigned*)alloc((size_t)E * sizeof(unsigned));  // 12.8MB; -> h16
    int*      col     = (int*)alloc((size_t)E * sizeof(int));            // 12.8MB; -> h3
    float*    agg     = (float*)alloc((size_t)n * 64 * sizeof(float));
    float*    hA      = (float*)alloc((size_t)n * 64 * sizeof(float));
    float*    agg4    = agg;            // layer-1 mean aliases agg
    f16*      h16     = (f16*)staging;  // fp16 mirror reuses staging after build
    (void)ws_size;

    const int BT = 256;
    const int EB = (E + 8191) / 8192;  // 391
    const int GB = (n + 63) / 64;      // sage_gemm grid

    // ---- CSR build ----
    hipMemsetAsync(bcnt, 0, (size_t)(K + 1) * sizeof(int), stream);
    bucket_count_kernel<<<EB, 512, 0, stream>>>(dst, bcnt, E, K);
    bscan_kernel<<<1, 1024, 0, stream>>>(bcnt, bbase, gcur, K, E);
    partition_kernel<<<EB, 512, 0, stream>>>(src, dst, gcur, staging, E, K);
    bucket_build_kernel<<<K, 256, 0, stream>>>(staging, bbase, rowptr, col, n, K);

    // ---- layer 1: x[N,4] -> hA[N,64] (+h16 mirror) ----
    pull4_kernel<<<(n + BT - 1) / BT, BT, 0, stream>>>(rowptr, col, (const float4*)x,
                                                       (float4*)agg4, n, E);
    sage_gemm_kernel<4, 64><<<GB, 256, 0, stream>>>(agg4, x, W1l, b1, W1r, hA, h16, n);

    // ---- layer 2: mean(h1_16) -> agg; gemm -> agg in-place (+h2_16 mirror) ----
    pull64h_kernel<<<(n + 3) / 4, 256, 0, stream>>>(rowptr, col, (const uint4*)h16,
                                                    (float4*)agg, n, E);
    sage_gemm_kernel<64, 64><<<GB, 256, 0, stream>>>(agg, hA, W2l, b2, W2r, agg, h16, n);

    // ---- layer 3: mean(h2_16) -> hA; gemm -> h3 (= col buffer) ----
    pull64h_kernel<<<(n + 3) / 4, 256, 0, stream>>>(rowptr, col, (const uint4*)h16,
                                                    (float4*)hA, n, E);
    float* h3 = (float*)col;
    sage_gemm_kernel<64, 32><<<GB, 256, 0, stream>>>(hA, agg, W3l, b3, W3r, h3, (f16*)nullptr, n);

    // ---- head ----
    head_kernel<<<(n + BT - 1) / BT, BT, 0, stream>>>(h3, W4, b4, W5, b5, out, n);
}